// Round 4
// baseline (374.273 us; speedup 1.0000x reference)
//
#include <hip/hip_runtime.h>
#include <hip/hip_bf16.h>

// Problem: B=32, L=1024, F=1024, H=1024, D=1024 — inputs fp32, OUTPUT fp32.
//   h1 = feat@W1 + b1; h2 = hidden@W2 + b2; att = tanh(h1 + h2[:,None,:])
//   score = att@Wp (+bp dropped: softmax shift-invariant; bp==0 anyway)
//   w = softmax_L(score); out[b][f] = sum_l w[b][l] * feat[b][l][f]
//
// ws footprint: 2.375 MB ONLY (round-3 failure was a ws overflow at 69.7 MB
// corrupting the harness's pristine input copies — post-timing divergence).

typedef __attribute__((ext_vector_type(8))) __bf16 bf16x8;
typedef __attribute__((ext_vector_type(4))) float f32x4;

#define BM 128
#define BN 128
#define BK 32
#define LDK 40  // padded LDS k-stride (elems): 80 B rows, 16B-aligned, 2-way banks (free)

static __device__ __forceinline__ ushort f2bf(float x) {  // RNE fp32->bf16
  unsigned u = __float_as_uint(x);
  return (ushort)((u + 0x7fffu + ((u >> 16) & 1u)) >> 16);
}

// ---------------- W1 fp32 [F][D] -> W1T bf16 [D][F] ----------------
__global__ __launch_bounds__(256) void transpose_w1_kernel(
    const float* __restrict__ W1, ushort* __restrict__ W1T) {
  __shared__ float t[64][65];
  const int tr = blockIdx.y, tc = blockIdx.x, tid = threadIdx.x;
  const int r = tid >> 4;          // 0..15
  const int c4 = (tid & 15) * 4;   // 0..60
#pragma unroll
  for (int p = 0; p < 4; ++p) {
    const int rr = p * 16 + r;
    float4 v = *(const float4*)(W1 + (size_t)(tr * 64 + rr) * 1024 + tc * 64 + c4);
    t[rr][c4] = v.x; t[rr][c4 + 1] = v.y; t[rr][c4 + 2] = v.z; t[rr][c4 + 3] = v.w;
  }
  __syncthreads();
  const int cc = tid >> 3;         // 0..31
  const int r8 = (tid & 7) * 8;    // 0..56
#pragma unroll
  for (int p = 0; p < 2; ++p) {
    const int c = p * 32 + cc;
    ushort tmp[8];
#pragma unroll
    for (int j = 0; j < 8; ++j) tmp[j] = f2bf(t[r8 + j][c]);
    *(int4*)(W1T + (size_t)(tc * 64 + c) * 1024 + tr * 64 + r8) = *(int4*)tmp;
  }
}

// ---------------- zero fp32 buffers ----------------
__global__ void zero_kernel(float* __restrict__ p) {
  p[(size_t)blockIdx.x * 256 + threadIdx.x] = 0.f;
}

// ---------------- h2[b][d] = hidden[b]@W2[:,d] + b2[d] (split-K atomics) ----------
__global__ __launch_bounds__(256) void h2_kernel(
    const float* __restrict__ hidden, const float* __restrict__ W2,
    const float* __restrict__ b2, float* __restrict__ h2) {
  const int d = blockIdx.x * 256 + threadIdx.x;
  const int b = blockIdx.y;
  const int k0 = blockIdx.z * 256;
  __shared__ float h[256];
  h[threadIdx.x] = hidden[b * 1024 + k0 + threadIdx.x];
  __syncthreads();
  float acc = (blockIdx.z == 0) ? b2[d] : 0.f;
#pragma unroll 8
  for (int k = 0; k < 256; ++k)
    acc += h[k] * W2[(size_t)(k0 + k) * 1024 + d];
  atomicAdd(&h2[b * 1024 + d], acc);
}

// ---------------- fused GEMM + tanh + dot(Wp) -> score (fp32 atomics) ----------------
// A (feat) is fp32 in HBM; converted to bf16 during LDS staging.
__global__ __launch_bounds__(256) void gemm_score_kernel(
    const float* __restrict__ feat,    // fp32 [32768][1024]
    const ushort* __restrict__ w1t,    // bf16 [1024][1024] = W1^T [d][f]
    const float* __restrict__ b1,      // [1024]
    const float* __restrict__ h2,      // [32][1024]
    const float* __restrict__ wp,      // [1024]
    float* __restrict__ score) {       // [32768]
  __shared__ ushort ldsA[BM * LDK];
  __shared__ ushort ldsB[BN * LDK];
  const int tid = threadIdx.x;
  const int row0 = blockIdx.x * BM;
  const int col0 = blockIdx.y * BN;
  const int b = row0 >> 10;  // 128-row tile never crosses a batch boundary

  const int wave = tid >> 6, lane = tid & 63;
  const int wm = wave & 1, wn = wave >> 1;
  const int lrow = lane & 15;   // m (A) / n (B) / col (C)
  const int quad = lane >> 4;   // k-group (A,B) / row-group (C)

  // A staging: each thread loads 16 contiguous fp32, converts, 2x b128 LDS writes.
  const int arow = tid >> 1;          // 0..127
  const int akof = (tid & 1) * 16;    // 0 or 16
  // B staging: each thread 16 bf16 (2 rows x int4).
  const int brow = tid >> 2;          // 0..63
  const int bkof = (tid & 3) * 8;     // 0,8,16,24

  f32x4 acc[4][4] = {};

  for (int k0 = 0; k0 < 1024; k0 += BK) {
    {  // A: fp32 -> bf16 -> LDS
      const float* ap = feat + (size_t)(row0 + arow) * 1024 + k0 + akof;
      float4 v0 = *(const float4*)(ap + 0);
      float4 v1 = *(const float4*)(ap + 4);
      float4 v2 = *(const float4*)(ap + 8);
      float4 v3 = *(const float4*)(ap + 12);
      __hip_bfloat162 c0 = __float22bfloat162_rn(make_float2(v0.x, v0.y));
      __hip_bfloat162 c1 = __float22bfloat162_rn(make_float2(v0.z, v0.w));
      __hip_bfloat162 c2 = __float22bfloat162_rn(make_float2(v1.x, v1.y));
      __hip_bfloat162 c3 = __float22bfloat162_rn(make_float2(v1.z, v1.w));
      __hip_bfloat162 c4 = __float22bfloat162_rn(make_float2(v2.x, v2.y));
      __hip_bfloat162 c5 = __float22bfloat162_rn(make_float2(v2.z, v2.w));
      __hip_bfloat162 c6 = __float22bfloat162_rn(make_float2(v3.x, v3.y));
      __hip_bfloat162 c7 = __float22bfloat162_rn(make_float2(v3.z, v3.w));
      int4 w0, w1;
      w0.x = *(int*)&c0; w0.y = *(int*)&c1; w0.z = *(int*)&c2; w0.w = *(int*)&c3;
      w1.x = *(int*)&c4; w1.y = *(int*)&c5; w1.z = *(int*)&c6; w1.w = *(int*)&c7;
      *(int4*)&ldsA[arow * LDK + akof] = w0;
      *(int4*)&ldsA[arow * LDK + akof + 8] = w1;
    }
#pragma unroll
    for (int p = 0; p < 2; ++p) {  // B: bf16 copy
      const int m = p * 64 + brow;
      *(int4*)&ldsB[m * LDK + bkof] =
          *(const int4*)(w1t + (size_t)(col0 + m) * 1024 + k0 + bkof);
    }
    __syncthreads();
    bf16x8 afrag[4], bfrag[4];
#pragma unroll
    for (int i = 0; i < 4; ++i)
      afrag[i] = *(const bf16x8*)&ldsA[(wm * 64 + i * 16 + lrow) * LDK + quad * 8];
#pragma unroll
    for (int j = 0; j < 4; ++j)
      bfrag[j] = *(const bf16x8*)&ldsB[(wn * 64 + j * 16 + lrow) * LDK + quad * 8];
#pragma unroll
    for (int i = 0; i < 4; ++i)
#pragma unroll
      for (int j = 0; j < 4; ++j)
        acc[i][j] = __builtin_amdgcn_mfma_f32_16x16x32_bf16(
            afrag[i], bfrag[j], acc[i][j], 0, 0, 0);
    __syncthreads();
  }

  // Epilogue: tanh(h1 + b1[d] + h2[b][d]) * Wp[d], reduce d within tile,
  // atomicAdd partials into score[row].
  float hbv[4], wpv[4];
#pragma unroll
  for (int j = 0; j < 4; ++j) {
    const int d = col0 + wn * 64 + j * 16 + lrow;
    hbv[j] = b1[d] + h2[b * 1024 + d];
    wpv[j] = wp[d];
  }
#pragma unroll
  for (int i = 0; i < 4; ++i) {
#pragma unroll
    for (int r = 0; r < 4; ++r) {
      float s = 0.f;
#pragma unroll
      for (int j = 0; j < 4; ++j)
        s += tanhf(acc[i][j][r] + hbv[j]) * wpv[j];
      s += __shfl_xor(s, 8);
      s += __shfl_xor(s, 4);
      s += __shfl_xor(s, 2);
      s += __shfl_xor(s, 1);
      if (lrow == 0)
        atomicAdd(&score[row0 + wm * 64 + i * 16 + quad * 4 + r], s);
    }
  }
}

// ---------------- softmax over L per b ----------------
__global__ __launch_bounds__(256) void softmax_kernel(
    const float* __restrict__ score, float* __restrict__ w) {
  const int b = blockIdx.x, tid = threadIdx.x;
  const int lane = tid & 63, wv = tid >> 6;
  __shared__ float sm[4], ss[4];
  float v[4];
  float mx = -1e30f;
#pragma unroll
  for (int i = 0; i < 4; ++i) {
    v[i] = score[b * 1024 + i * 256 + tid];
    mx = fmaxf(mx, v[i]);
  }
#pragma unroll
  for (int off = 32; off; off >>= 1) mx = fmaxf(mx, __shfl_xor(mx, off));
  if (lane == 0) sm[wv] = mx;
  __syncthreads();
  mx = fmaxf(fmaxf(sm[0], sm[1]), fmaxf(sm[2], sm[3]));
  float sum = 0.f;
#pragma unroll
  for (int i = 0; i < 4; ++i) {
    v[i] = __expf(v[i] - mx);
    sum += v[i];
  }
#pragma unroll
  for (int off = 32; off; off >>= 1) sum += __shfl_xor(sum, off);
  if (lane == 0) ss[wv] = sum;
  __syncthreads();
  const float inv = 1.f / (ss[0] + ss[1] + ss[2] + ss[3]);
#pragma unroll
  for (int i = 0; i < 4; ++i) w[b * 1024 + i * 256 + tid] = v[i] * inv;
}

// ---------------- out[b][f] += sum_{l in chunk} w[b][l]*feat[b][l][f] (fp32) --------
__global__ __launch_bounds__(256) void context_kernel(
    const float* __restrict__ w, const float* __restrict__ feat,
    float* __restrict__ out) {
  const int b = blockIdx.y;
  const int l0 = blockIdx.x * 128;
  const int f0 = threadIdx.x * 4;  // 4 f's per thread (16 B fp32 loads)
  __shared__ float wl[128];
  if (threadIdx.x < 128) wl[threadIdx.x] = w[b * 1024 + l0 + threadIdx.x];
  __syncthreads();
  const float* fb = feat + (size_t)b * 1048576 + (size_t)l0 * 1024 + f0;
  float a0 = 0.f, a1 = 0.f, a2 = 0.f, a3 = 0.f;
#pragma unroll 4
  for (int l = 0; l < 128; ++l) {
    float4 v = *(const float4*)(fb + (size_t)l * 1024);
    const float wv = wl[l];
    a0 += wv * v.x;
    a1 += wv * v.y;
    a2 += wv * v.z;
    a3 += wv * v.w;
  }
  float* dst = out + b * 1024 + f0;
  atomicAdd(dst + 0, a0);
  atomicAdd(dst + 1, a1);
  atomicAdd(dst + 2, a2);
  atomicAdd(dst + 3, a3);
}

extern "C" void kernel_launch(void* const* d_in, const int* in_sizes, int n_in,
                              void* d_out, int out_size, void* d_ws, size_t ws_size,
                              hipStream_t stream) {
  const float* feat   = (const float*)d_in[0];  // [32,1024,1024]
  const float* hidden = (const float*)d_in[1];  // [32,1024]
  const float* W1     = (const float*)d_in[2];  // [1024,1024]
  const float* b1     = (const float*)d_in[3];  // [1024]
  const float* W2     = (const float*)d_in[4];  // [1024,1024]
  const float* b2     = (const float*)d_in[5];  // [1024]
  const float* Wp     = (const float*)d_in[6];  // [1024]
  // d_in[7] = bp: dropped (softmax shift-invariant; also zero)
  float* out = (float*)d_out;                   // fp32 [32,1024]

  char* ws = (char*)d_ws;
  ushort* w1t  = (ushort*)ws;                    // 2 MB bf16
  float* score = (float*)(ws + 2097152);         // 128 KB
  float* h2buf = (float*)(ws + 2097152 + 131072);// 128 KB (contiguous after score)
  float* wts   = (float*)(ws + 2097152 + 262144);// 128 KB
  // total ws use: 2.375 MB

  transpose_w1_kernel<<<dim3(16, 16), 256, 0, stream>>>(W1, w1t);
  zero_kernel<<<256, 256, 0, stream>>>(score);  // zeroes score + h2buf (contiguous)
  zero_kernel<<<128, 256, 0, stream>>>(out);    // d_out is poisoned 0xAA pre-launch
  h2_kernel<<<dim3(4, 32, 4), 256, 0, stream>>>(hidden, W2, b2, h2buf);
  gemm_score_kernel<<<dim3(256, 8), 256, 0, stream>>>(feat, w1t, b1, h2buf, Wp,
                                                      score);
  softmax_kernel<<<32, 256, 0, stream>>>(score, wts);
  context_kernel<<<dim3(8, 32), 256, 0, stream>>>(wts, feat, out);
}